// Round 21
// baseline (29.546 us; speedup 1.0000x reference)
//
#include <hip/hip_runtime.h>
#include <cstddef>
#include <cstdint>

#define SS 2048
#define DD 128
#define NB 8

typedef _Float16 half8 __attribute__((ext_vector_type(8)));
typedef __fp16 fp16x2 __attribute__((ext_vector_type(2)));
typedef __attribute__((ext_vector_type(16))) float f32x16;

#if __has_builtin(__builtin_amdgcn_exp2f)
#define EXP2F(x) __builtin_amdgcn_exp2f(x)
#else
#define EXP2F(x) exp2f(x)
#endif

// ---- workspace layout (bytes) ----
#define WS_A2   0                      // NB*SS f32 (pre-folded a*log2e/sqrt(d))
#define WS_KV   (NB*SS*4)              // NB*SS f32
#define WS_XF   (2*NB*SS*4)            // 131072: fp16 fragment-major X^T
#define BATCH_B (SS*DD*2)              // 512 KiB per batch
#define WS_NEED (size_t)(WS_XF + (size_t)NB*BATCH_B)   // ~4.33 MB
// fallback-only scratch (fits in WS_XF area)
#define WS_KMX  (WS_XF)
#define WS_KMN  (WS_XF + 128)

// Fragment-major layout for X^T fp16, per batch:
//   element X[t][d]:  T=t>>7, t'=t&127, ks=t'>>4, hh=(t'>>3)&1, j=t'&7,
//                     nt=d>>5, lm=d&31, lane=lm+(hh<<5)
//   byte = (T*8+ks)*4096 + nt*1024 + lane*16 + j*2
// => tile T is one contiguous 32 KiB block; frag (ks,nt) = 1 KiB.

// ---------------- Kernel 1: fused projections + X->fp16 fragment store -----
__global__ __launch_bounds__(256) void prep(
    const float* __restrict__ X, const float* __restrict__ rotp,
    const float* __restrict__ entp, uint8_t* __restrict__ ws, int do_x) {
  __shared__ __align__(16) uint8_t lbuf[128 * 80];  // 10 KiB
  const int blk = blockIdx.x;
  const int b = blk & 7;
  const int rc = blk >> 3;
  const int tid = threadIdx.x;
  const int d4 = (tid & 31) * 4;
  float* a2out = (float*)(ws + WS_A2);
  float* kout = (float*)(ws + WS_KV);

  const float4 f0 = *reinterpret_cast<const float4*>(rotp + d4 * 3);
  const float4 f1 = *reinterpret_cast<const float4*>(rotp + d4 * 3 + 4);
  const float4 f2 = *reinterpret_cast<const float4*>(rotp + d4 * 3 + 8);
  const float rs0 = f0.x + f0.y + f0.z;
  const float rs1 = f0.w + f1.x + f1.y;
  const float rs2 = f1.z + f1.w + f2.x;
  const float rs3 = f2.y + f2.z + f2.w;
  const float4 e4 = *reinterpret_cast<const float4*>(entp + d4);

#pragma unroll
  for (int rnd = 0; rnd < 4; ++rnd) {
    const int t31 = rnd * 8 + (tid >> 5);           // 0..31 within block
    const int tg = rc * 32 + t31;                   // t within batch
    const float4 xv =
        *reinterpret_cast<const float4*>(X + ((size_t)b * SS + tg) * DD + d4);
    float av = xv.x * rs0 + xv.y * rs1 + xv.z * rs2 + xv.w * rs3;
    float kv = xv.x * e4.x + xv.y * e4.y + xv.z * e4.z + xv.w * e4.w;
#pragma unroll
    for (int off = 16; off > 0; off >>= 1) {
      av += __shfl_xor(av, off, 64);
      kv += __shfl_xor(kv, off, 64);
    }
    if ((tid & 31) == 0) {
      a2out[b * SS + tg] = av * (0.08838834764831845f * 1.4426950408889634f);
      kout[b * SS + tg] = kv;
    }
    if (do_x) {
      const float vv[4] = {xv.x, xv.y, xv.z, xv.w};
#pragma unroll
      for (int i = 0; i < 4; ++i)
        *reinterpret_cast<_Float16*>(lbuf + (d4 + i) * 80 + t31 * 2) =
            (_Float16)vv[i];
    }
  }

  if (do_x) {
    __syncthreads();
    const int T = rc >> 2;
    const int wfb = (rc & 3) * 2;
    uint8_t* outb = ws + WS_XF + (size_t)b * BATCH_B + (T * 8 + wfb) * 4096;
    const int nt = tid >> 6;
    const int lane = tid & 63;
    const int hh = lane >> 5;
    const int d = nt * 32 + (lane & 31);
#pragma unroll
    for (int wfl = 0; wfl < 2; ++wfl) {
      const half8 v = *reinterpret_cast<const half8*>(
          lbuf + d * 80 + (wfl * 16 + hh * 8) * 2);
      *reinterpret_cast<half8*>(outb + wfl * 4096 + nt * 1024 + lane * 16) = v;
    }
  }
}

// ---------------- async global->LDS helper ----------------
typedef __attribute__((address_space(3))) unsigned int lds_u32;
typedef const __attribute__((address_space(1))) unsigned int glb_u32;
__device__ __forceinline__ void gload16(const void* g, void* l) {
  __builtin_amdgcn_global_load_lds((glb_u32*)g, (lds_u32*)l, 16, 0, 0);
}

// ---------------- Kernel 2: MFMA softmax-weighted PV ----------------
// R14/R20 config (512 blocks, 2/CU, 8 waves, s-tile 32) + LDS frag staging
// per the 2-phase template: stage NEXT 32KB tile (4x global_load_lds) before
// computing the CURRENT one; one barrier per iter; the co-resident block
// covers the barrier's vmcnt drain (this is what R17's 1-block/CU version
// lacked). Also frees 32 VGPRs (no register frag prefetch) -> no spill
// pressure at the 128/wave cap. k stays in LDS (R20's win).
__global__ __launch_bounds__(512, 4) void attn_mfma(
    const uint8_t* __restrict__ ws, float* __restrict__ out) {
  __shared__ __align__(16) uint8_t smem[65536];  // 2x32KB frag dbuf; comb reuse
  __shared__ float dl[8 * 32];
  __shared__ float smx[8], smn[8];
  __shared__ __align__(16) float kls[SS];        // 8 KiB batch k-vector
  const int tid = threadIdx.x;
  const int w = tid >> 6;
  const int lane = tid & 63;
  const int lm = lane & 31;
  const int h = lane >> 5;
  const int blk = blockIdx.x;
  const int b = blk & 7;
  const int s0 = (blk >> 3) * 32;

  const float* a2 = (const float*)(ws + WS_A2) + b * SS;
  const float* kb = (const float*)(ws + WS_KV) + b * SS;
  const uint8_t* xf = ws + WS_XF + (size_t)b * BATCH_B;

#define STAGE(Tn, bb)                                                         \
  {                                                                           \
    const uint8_t* src_ = xf + (size_t)(Tn) * 32768 + tid * 16;               \
    uint8_t* dst_ = smem + (bb) + tid * 16;                                   \
    gload16(src_, dst_);                                                      \
    gload16(src_ + 8192, dst_ + 8192);                                        \
    gload16(src_ + 16384, dst_ + 16384);                                      \
    gload16(src_ + 24576, dst_ + 24576);                                      \
  }

  // prologue: stage tile 0 into buf0 (latency hidden under minmax reduce)
  STAGE(0, 0);

  // per-batch kmax/kmin (512 thr x 4) + stage k into LDS
  const float4 k4 = *reinterpret_cast<const float4*>(kb + tid * 4);
  *reinterpret_cast<float4*>(kls + tid * 4) = k4;
  float mx = fmaxf(fmaxf(k4.x, k4.y), fmaxf(k4.z, k4.w));
  float mn = fminf(fminf(k4.x, k4.y), fminf(k4.z, k4.w));
#pragma unroll
  for (int off = 32; off > 0; off >>= 1) {
    mx = fmaxf(mx, __shfl_xor(mx, off, 64));
    mn = fminf(mn, __shfl_xor(mn, off, 64));
  }
  if (lane == 0) { smx[w] = mx; smn[w] = mn; }
  const float ga = a2[s0 + lm];
  __syncthreads();  // drains stage-0 vmcnt; kls/smx/smn visible
  mx = smx[0]; mn = smn[0];
#pragma unroll
  for (int q = 1; q < 8; ++q) { mx = fmaxf(mx, smx[q]); mn = fminf(mn, smn[q]); }
  const float gm = fmaxf(ga * mx, ga * mn);
  float gden = 0.0f;

  f32x16 acc[4];
#pragma unroll
  for (int nt = 0; nt < 4; ++nt)
#pragma unroll
    for (int r = 0; r < 16; ++r) acc[nt][r] = 0.0f;

  const float* kp0 = kls + w * 16 + h * 8;  // LDS, broadcast per half-wave
  int cur = 0;

  for (int T = 0; T < 16; ++T) {
    if (T < 15) STAGE(T + 1, (cur ^ 1) << 15);  // issue-early, drained at barrier
    // A-gen: w(s=lm, t = T*128 + w*16 + h*8 + j), k from LDS
    const float* kp = kp0 + T * 128;
    const float4 ka = *reinterpret_cast<const float4*>(kp);
    const float4 kc = *reinterpret_cast<const float4*>(kp + 4);
    const float kv8[8] = {ka.x, ka.y, ka.z, ka.w, kc.x, kc.y, kc.z, kc.w};
    float e0[8];
#pragma unroll
    for (int j = 0; j < 8; ++j) {
      e0[j] = EXP2F(fmaf(ga, kv8[j], -gm));
      gden += e0[j];
    }
    union { half8 v; fp16x2 p[4]; } wa;
#pragma unroll
    for (int q = 0; q < 4; ++q)
      wa.p[q] = __builtin_amdgcn_cvt_pkrtz(e0[2 * q], e0[2 * q + 1]);
    // B-frags from LDS (16B/lane linear ds_read_b128, conflict-free)
    const uint8_t* bbuf = smem + (cur << 15) + w * 4096 + lane * 16;
    __builtin_amdgcn_s_setprio(1);
#pragma unroll
    for (int nt = 0; nt < 4; ++nt) {
      const half8 bf = *reinterpret_cast<const half8*>(bbuf + nt * 1024);
      acc[nt] = __builtin_amdgcn_mfma_f32_32x32x16_f16(wa.v, bf, acc[nt], 0, 0, 0);
    }
    __builtin_amdgcn_s_setprio(0);
    __syncthreads();  // all reads done + staged loads landed; swap safe
    cur ^= 1;
  }
#undef STAGE

  // ---- combine: waves 0-3 -> grp0, 4-7 -> grp1 (comb overlays smem) ----
  float* comb0 = reinterpret_cast<float*>(smem);   // 2 x 16 KiB
  gden += __shfl_xor(gden, 32, 64);
  if (lane < 32) dl[w * 32 + lane] = gden;
#pragma unroll
  for (int p = 0; p < 4; ++p) {
    const int grp = w >> 2;       // 0 or 1
    if ((w & 3) == p) {
      float* cb = comb0 + grp * 32 * 128;
#pragma unroll
      for (int nt = 0; nt < 4; ++nt)
#pragma unroll
        for (int r = 0; r < 16; ++r) {
          const int rr = (r & 3) + 8 * (r >> 2) + 4 * h;
          const int i0 = rr * 128 + nt * 32 + lm;
          if (p == 0) cb[i0] = acc[nt][r];
          else        cb[i0] += acc[nt][r];
        }
    }
    __syncthreads();
  }

  // ---- epilogue: sum copies, divide by denominator, store ----
  const int r = tid >> 4;          // 0..31
  const int cg = (tid & 15) * 8;   // 0..120
  float den = 0.0f;
#pragma unroll
  for (int q = 0; q < 8; ++q) den += dl[q * 32 + r];
  const float inv = 1.0f / den;
  float* orow = out + ((size_t)b * SS + s0 + r) * DD + cg;
#pragma unroll
  for (int q = 0; q < 2; ++q) {
    const float4 vA = *reinterpret_cast<const float4*>(comb0 + r * 128 + cg + q * 4);
    const float4 vB = *reinterpret_cast<const float4*>(comb0 + 32 * 128 + r * 128 + cg + q * 4);
    *reinterpret_cast<float4*>(orow + q * 4) =
        make_float4((vA.x + vB.x) * inv, (vA.y + vB.y) * inv,
                    (vA.z + vB.z) * inv, (vA.w + vB.w) * inv);
  }
}

// ---------------- fallback (ws too small): fp32 path ----------------
__global__ __launch_bounds__(256) void kminmax(const float* __restrict__ kvec,
                                               float* __restrict__ kmx,
                                               float* __restrict__ kmn) {
  const int b = blockIdx.x;
  const int tid = threadIdx.x;
  float mx = -1e30f, mn = 1e30f;
  for (int i = tid; i < SS; i += 256) {
    const float v = kvec[b * SS + i];
    mx = fmaxf(mx, v);
    mn = fminf(mn, v);
  }
#pragma unroll
  for (int off = 32; off > 0; off >>= 1) {
    mx = fmaxf(mx, __shfl_xor(mx, off, 64));
    mn = fminf(mn, __shfl_xor(mn, off, 64));
  }
  __shared__ float smx[4], smn[4];
  const int wid = tid >> 6, lane = tid & 63;
  if (lane == 0) { smx[wid] = mx; smn[wid] = mn; }
  __syncthreads();
  if (tid == 0) {
    kmx[b] = fmaxf(fmaxf(smx[0], smx[1]), fmaxf(smx[2], smx[3]));
    kmn[b] = fminf(fminf(smn[0], smn[1]), fminf(smn[2], smn[3]));
  }
}

__global__ __launch_bounds__(256) void attn_main(
    const float* __restrict__ X, const float* __restrict__ a2,
    const float* __restrict__ kvec, const float* __restrict__ kmx,
    const float* __restrict__ kmn, float* __restrict__ out) {
  __shared__ float xs[64 * DD];
  __shared__ float wt[64 * 32];
  __shared__ float denp[8 * 32];
  const int tid = threadIdx.x;
  const int tx = tid & 15;
  const int ty = (tid >> 4) & 3;
  const int tz = tid >> 6;
  const int b = blockIdx.y;
  const int s0 = blockIdx.x * 32;
  const int sg = tid & 31;
  const int tq = tid >> 5;
  const float ga = a2[b * SS + s0 + sg];
  const float gm = fmaxf(ga * kmx[b], ga * kmn[b]);
  float gden = 0.0f;
  float acc[8][8];
#pragma unroll
  for (int r = 0; r < 8; ++r)
#pragma unroll
    for (int c = 0; c < 8; ++c) acc[r][c] = 0.0f;
  const float* xb = X + (size_t)b * SS * DD;
  const float* kb = kvec + b * SS;
  for (int t0 = 0; t0 < SS; t0 += 64) {
    __syncthreads();
#pragma unroll
    for (int rnd = 0; rnd < 8; ++rnd) {
      const int idx = rnd * 1024 + tid * 4;
      *reinterpret_cast<float4*>(xs + idx) =
          *reinterpret_cast<const float4*>(xb + t0 * DD + idx);
    }
#pragma unroll
    for (int j = 0; j < 8; ++j) {
      const float kt = kb[t0 + tq * 8 + j];
      const float wv = exp2f(fmaf(ga, kt, -gm));
      wt[(tq * 8 + j) * 32 + sg] = wv;
      gden += wv;
    }
    __syncthreads();
#pragma unroll 4
    for (int ti = 0; ti < 16; ++ti) {
      const int tl = tz * 16 + ti;
      const float4 x0 = *reinterpret_cast<const float4*>(xs + tl * DD + tx * 8);
      const float4 x1 = *reinterpret_cast<const float4*>(xs + tl * DD + tx * 8 + 4);
      const float4 w0 = *reinterpret_cast<const float4*>(wt + tl * 32 + ty * 8);
      const float4 w1 = *reinterpret_cast<const float4*>(wt + tl * 32 + ty * 8 + 4);
      const float xr[8] = {x0.x, x0.y, x0.z, x0.w, x1.x, x1.y, x1.z, x1.w};
      const float wr[8] = {w0.x, w0.y, w0.z, w0.w, w1.x, w1.y, w1.z, w1.w};
#pragma unroll
      for (int r = 0; r < 8; ++r)
#pragma unroll
        for (int c = 0; c < 8; ++c) acc[r][c] = fmaf(wr[r], xr[c], acc[r][c]);
    }
  }
  __syncthreads();
  denp[tq * 32 + sg] = gden;
  for (int p = 1; p < 4; ++p) {
    __syncthreads();
    if (tz == p) {
#pragma unroll
      for (int r = 0; r < 8; ++r) {
        const int sl = ty * 8 + r;
        *reinterpret_cast<float4*>(xs + sl * DD + tx * 8) =
            make_float4(acc[r][0], acc[r][1], acc[r][2], acc[r][3]);
        *reinterpret_cast<float4*>(xs + sl * DD + tx * 8 + 4) =
            make_float4(acc[r][4], acc[r][5], acc[r][6], acc[r][7]);
      }
    }
    __syncthreads();
    if (tz == 0) {
#pragma unroll
      for (int r = 0; r < 8; ++r) {
        const int sl = ty * 8 + r;
        const float4 v0 = *reinterpret_cast<const float4*>(xs + sl * DD + tx * 8);
        const float4 v1 = *reinterpret_cast<const float4*>(xs + sl * DD + tx * 8 + 4);
        acc[r][0] += v0.x; acc[r][1] += v0.y; acc[r][2] += v0.z; acc[r][3] += v0.w;
        acc[r][4] += v1.x; acc[r][5] += v1.y; acc[r][6] += v1.z; acc[r][7] += v1.w;
      }
    }
  }
  if (tz == 0) {
#pragma unroll
    for (int r = 0; r < 8; ++r) {
      const int sl = ty * 8 + r;
      float den = 0.0f;
#pragma unroll
      for (int q = 0; q < 8; ++q) den += denp[q * 32 + sl];
      const float inv = 1.0f / den;
      float* orow = out + ((size_t)b * SS + s0 + sl) * DD + tx * 8;
      *reinterpret_cast<float4*>(orow) =
          make_float4(acc[r][0] * inv, acc[r][1] * inv, acc[r][2] * inv, acc[r][3] * inv);
      *reinterpret_cast<float4*>(orow + 4) =
          make_float4(acc[r][4] * inv, acc[r][5] * inv, acc[r][6] * inv, acc[r][7] * inv);
    }
  }
}

extern "C" void kernel_launch(void* const* d_in, const int* in_sizes, int n_in,
                              void* d_out, int out_size, void* d_ws, size_t ws_size,
                              hipStream_t stream) {
  const float* X = (const float*)d_in[0];
  const float* rotp = (const float*)d_in[1];
  const float* entp = (const float*)d_in[2];
  float* out = (float*)d_out;
  uint8_t* ws = (uint8_t*)d_ws;

  if (ws_size >= WS_NEED) {
    prep<<<512, 256, 0, stream>>>(X, rotp, entp, ws, 1);
    attn_mfma<<<512, 512, 0, stream>>>((const uint8_t*)ws, out);
  } else {
    float* a2 = (float*)(ws + WS_A2);
    float* kv = (float*)(ws + WS_KV);
    float* kmxp = (float*)(ws + WS_KMX);
    float* kmnp = (float*)(ws + WS_KMN);
    prep<<<512, 256, 0, stream>>>(X, rotp, entp, ws, 0);
    kminmax<<<NB, 256, 0, stream>>>(kv, kmxp, kmnp);
    attn_main<<<dim3(SS / 32, NB), 256, 0, stream>>>(X, a2, kv, kmxp, kmnp, out);
  }
}

// Round 22
// 26.929 us; speedup vs baseline: 1.0972x; 1.0972x over previous
//
#include <hip/hip_runtime.h>
#include <cstddef>
#include <cstdint>

#define SS 2048
#define DD 128
#define NB 8

typedef _Float16 half8 __attribute__((ext_vector_type(8)));
typedef __fp16 fp16x2 __attribute__((ext_vector_type(2)));
typedef __attribute__((ext_vector_type(16))) float f32x16;

#if __has_builtin(__builtin_amdgcn_exp2f)
#define EXP2F(x) __builtin_amdgcn_exp2f(x)
#else
#define EXP2F(x) exp2f(x)
#endif

// ---- workspace layout (bytes) ----
#define WS_A2   0                      // NB*SS f32 (pre-folded a*log2e/sqrt(d))
#define WS_KV   (NB*SS*4)              // NB*SS f32
#define WS_XF   (2*NB*SS*4)            // 131072: fp16 fragment-major X^T
#define BATCH_B (SS*DD*2)              // 512 KiB per batch
#define WS_NEED (size_t)(WS_XF + (size_t)NB*BATCH_B)   // ~4.33 MB
// fallback-only scratch (fits in WS_XF area)
#define WS_KMX  (WS_XF)
#define WS_KMN  (WS_XF + 128)

// Fragment-major layout for X^T fp16, per batch:
//   element X[t][d]:  T=t>>7, t'=t&127, ks=t'>>4, hh=(t'>>3)&1, j=t'&7,
//                     nt=d>>5, lm=d&31, lane=lm+(hh<<5)
//   byte = (T*8+ks)*4096 + nt*1024 + lane*16 + j*2
// => a wave's B-frag (T,ks,nt) is ONE contiguous 1 KiB block (dwordx4/lane).

// ---------------- Kernel 1: fused projections + X->fp16 fragment store -----
__global__ __launch_bounds__(256) void prep(
    const float* __restrict__ X, const float* __restrict__ rotp,
    const float* __restrict__ entp, uint8_t* __restrict__ ws, int do_x) {
  __shared__ __align__(16) uint8_t lbuf[128 * 80];  // 10 KiB
  const int blk = blockIdx.x;
  const int b = blk & 7;
  const int rc = blk >> 3;
  const int tid = threadIdx.x;
  const int d4 = (tid & 31) * 4;
  float* a2out = (float*)(ws + WS_A2);
  float* kout = (float*)(ws + WS_KV);

  const float4 f0 = *reinterpret_cast<const float4*>(rotp + d4 * 3);
  const float4 f1 = *reinterpret_cast<const float4*>(rotp + d4 * 3 + 4);
  const float4 f2 = *reinterpret_cast<const float4*>(rotp + d4 * 3 + 8);
  const float rs0 = f0.x + f0.y + f0.z;
  const float rs1 = f0.w + f1.x + f1.y;
  const float rs2 = f1.z + f1.w + f2.x;
  const float rs3 = f2.y + f2.z + f2.w;
  const float4 e4 = *reinterpret_cast<const float4*>(entp + d4);

#pragma unroll
  for (int rnd = 0; rnd < 4; ++rnd) {
    const int t31 = rnd * 8 + (tid >> 5);           // 0..31 within block
    const int tg = rc * 32 + t31;                   // t within batch
    const float4 xv =
        *reinterpret_cast<const float4*>(X + ((size_t)b * SS + tg) * DD + d4);
    float av = xv.x * rs0 + xv.y * rs1 + xv.z * rs2 + xv.w * rs3;
    float kv = xv.x * e4.x + xv.y * e4.y + xv.z * e4.z + xv.w * e4.w;
#pragma unroll
    for (int off = 16; off > 0; off >>= 1) {
      av += __shfl_xor(av, off, 64);
      kv += __shfl_xor(kv, off, 64);
    }
    if ((tid & 31) == 0) {
      a2out[b * SS + tg] = av * (0.08838834764831845f * 1.4426950408889634f);
      kout[b * SS + tg] = kv;
    }
    if (do_x) {
      const float vv[4] = {xv.x, xv.y, xv.z, xv.w};
#pragma unroll
      for (int i = 0; i < 4; ++i)
        *reinterpret_cast<_Float16*>(lbuf + (d4 + i) * 80 + t31 * 2) =
            (_Float16)vv[i];
    }
  }

  if (do_x) {
    __syncthreads();
    const int T = rc >> 2;
    const int wfb = (rc & 3) * 2;
    uint8_t* outb = ws + WS_XF + (size_t)b * BATCH_B + (T * 8 + wfb) * 4096;
    const int nt = tid >> 6;
    const int lane = tid & 63;
    const int hh = lane >> 5;
    const int d = nt * 32 + (lane & 31);
#pragma unroll
    for (int wfl = 0; wfl < 2; ++wfl) {
      const half8 v = *reinterpret_cast<const half8*>(
          lbuf + d * 80 + (wfl * 16 + hh * 8) * 2);
      *reinterpret_cast<half8*>(outb + wfl * 4096 + nt * 1024 + lane * 16) = v;
    }
  }
}

// ---------------- Kernel 2: MFMA softmax-weighted PV (best: R20, 27.03us) ---
// 512 blocks: b = blk&7 (XCD affinity), s0 = (blk>>3)*32 -> 2 blocks/CU,
// 4 waves/SIMD. 8 waves = 8 disjoint 16-t k-slices per 128-t tile.
// B-frags global->VGPR 1-deep prefetch + per-wave T-phase stagger;
// k-vector staged in LDS (broadcast ds_read, 0 VGPR cost); bare v_exp_f32;
// packed RTZ f32->f16 cvt; no main-loop barriers.
__global__ __launch_bounds__(512, 4) void attn_mfma(
    const uint8_t* __restrict__ ws, float* __restrict__ out) {
  __shared__ float comb[2][32 * 128];  // 32 KiB
  __shared__ float dl[8 * 32];
  __shared__ float smx[8], smn[8];
  __shared__ __align__(16) float kls[SS];  // 8 KiB: whole batch k-vector
  const int tid = threadIdx.x;
  const int w = tid >> 6;
  const int lane = tid & 63;
  const int lm = lane & 31;
  const int h = lane >> 5;
  const int blk = blockIdx.x;
  const int b = blk & 7;
  const int s0 = (blk >> 3) * 32;

  const float* a2 = (const float*)(ws + WS_A2) + b * SS;
  const float* kb = (const float*)(ws + WS_KV) + b * SS;
  const uint8_t* xf = ws + WS_XF + (size_t)b * BATCH_B;

  // per-batch kmax/kmin (512 thr x 4) + stage k into LDS
  const float4 k4 = *reinterpret_cast<const float4*>(kb + tid * 4);
  *reinterpret_cast<float4*>(kls + tid * 4) = k4;
  float mx = fmaxf(fmaxf(k4.x, k4.y), fmaxf(k4.z, k4.w));
  float mn = fminf(fminf(k4.x, k4.y), fminf(k4.z, k4.w));
#pragma unroll
  for (int off = 32; off > 0; off >>= 1) {
    mx = fmaxf(mx, __shfl_xor(mx, off, 64));
    mn = fminf(mn, __shfl_xor(mn, off, 64));
  }
  if (lane == 0) { smx[w] = mx; smn[w] = mn; }
  const float ga = a2[s0 + lm];
  __syncthreads();  // kls + smx/smn visible
  mx = smx[0]; mn = smn[0];
#pragma unroll
  for (int q = 1; q < 8; ++q) { mx = fmaxf(mx, smx[q]); mn = fminf(mn, smn[q]); }
  const float gm = fmaxf(ga * mx, ga * mn);
  float gden = 0.0f;

  f32x16 acc[4];
#pragma unroll
  for (int nt = 0; nt < 4; ++nt)
#pragma unroll
    for (int r = 0; r < 16; ++r) acc[nt][r] = 0.0f;

  const uint8_t* wb = xf + w * 4096 + lane * 16;  // my frag base
  const float* kp0 = kls + w * 16 + h * 8;        // LDS, broadcast per h-half
  const int tph = 2 * w;                          // per-wave phase offset

  half8 bfA[4], bfB[4];
  {
    const int T0 = tph & 15;
#pragma unroll
    for (int nt = 0; nt < 4; ++nt)
      bfA[nt] = *reinterpret_cast<const half8*>(wb + T0 * 32768 + nt * 1024);
  }

#define ABODY(II, BFP, BFN)                                                   \
  {                                                                           \
    if ((II) + 1 < 16) {                                                      \
      const int Tn = ((II) + 1 + tph) & 15;                                   \
      const uint8_t* nb_ = wb + Tn * 32768;                                   \
      _Pragma("unroll") for (int nt = 0; nt < 4; ++nt)                        \
          BFN[nt] = *reinterpret_cast<const half8*>(nb_ + nt * 1024);         \
    }                                                                         \
    const int Tc = ((II) + tph) & 15;                                         \
    const float* kp = kp0 + Tc * 128;                                         \
    const float4 ka = *reinterpret_cast<const float4*>(kp);                   \
    const float4 kc = *reinterpret_cast<const float4*>(kp + 4);               \
    const float kv8[8] = {ka.x, ka.y, ka.z, ka.w, kc.x, kc.y, kc.z, kc.w};    \
    float e0[8];                                                              \
    _Pragma("unroll") for (int j = 0; j < 8; ++j) {                           \
      e0[j] = EXP2F(fmaf(ga, kv8[j], -gm));                                   \
      gden += e0[j];                                                          \
    }                                                                         \
    union { half8 v; fp16x2 p[4]; } wa;                                       \
    _Pragma("unroll") for (int q = 0; q < 4; ++q)                             \
        wa.p[q] = __builtin_amdgcn_cvt_pkrtz(e0[2 * q], e0[2 * q + 1]);       \
    __builtin_amdgcn_s_setprio(1);                                            \
    _Pragma("unroll") for (int nt = 0; nt < 4; ++nt)                          \
        acc[nt] = __builtin_amdgcn_mfma_f32_32x32x16_f16(wa.v, BFP[nt],       \
                                                         acc[nt], 0, 0, 0);   \
    __builtin_amdgcn_s_setprio(0);                                            \
  }

  for (int i = 0; i < 16; i += 2) {
    ABODY(i, bfA, bfB);
    ABODY(i + 1, bfB, bfA);
  }
#undef ABODY

  // ---- combine: waves 0-3 -> comb[0], 4-7 -> comb[1], 4 phases ----
  gden += __shfl_xor(gden, 32, 64);
  if (lane < 32) dl[w * 32 + lane] = gden;
#pragma unroll
  for (int p = 0; p < 4; ++p) {
    const int grp = w >> 2;       // 0 or 1
    if ((w & 3) == p) {
      float* cb = comb[grp];
#pragma unroll
      for (int nt = 0; nt < 4; ++nt)
#pragma unroll
        for (int r = 0; r < 16; ++r) {
          const int rr = (r & 3) + 8 * (r >> 2) + 4 * h;
          const int i0 = rr * 128 + nt * 32 + lm;
          if (p == 0) cb[i0] = acc[nt][r];
          else        cb[i0] += acc[nt][r];
        }
    }
    __syncthreads();
  }

  // ---- epilogue: sum copies, divide by denominator, store ----
  const int r = tid >> 4;          // 0..31
  const int cg = (tid & 15) * 8;   // 0..120
  float den = 0.0f;
#pragma unroll
  for (int q = 0; q < 8; ++q) den += dl[q * 32 + r];
  const float inv = 1.0f / den;
  float* orow = out + ((size_t)b * SS + s0 + r) * DD + cg;
#pragma unroll
  for (int q = 0; q < 2; ++q) {
    const float4 vA = *reinterpret_cast<const float4*>(&comb[0][r * 128 + cg + q * 4]);
    const float4 vB = *reinterpret_cast<const float4*>(&comb[1][r * 128 + cg + q * 4]);
    *reinterpret_cast<float4*>(orow + q * 4) =
        make_float4((vA.x + vB.x) * inv, (vA.y + vB.y) * inv,
                    (vA.z + vB.z) * inv, (vA.w + vB.w) * inv);
  }
}

// ---------------- fallback (ws too small): fp32 path ----------------
__global__ __launch_bounds__(256) void kminmax(const float* __restrict__ kvec,
                                               float* __restrict__ kmx,
                                               float* __restrict__ kmn) {
  const int b = blockIdx.x;
  const int tid = threadIdx.x;
  float mx = -1e30f, mn = 1e30f;
  for (int i = tid; i < SS; i += 256) {
    const float v = kvec[b * SS + i];
    mx = fmaxf(mx, v);
    mn = fminf(mn, v);
  }
#pragma unroll
  for (int off = 32; off > 0; off >>= 1) {
    mx = fmaxf(mx, __shfl_xor(mx, off, 64));
    mn = fminf(mn, __shfl_xor(mn, off, 64));
  }
  __shared__ float smx[4], smn[4];
  const int wid = tid >> 6, lane = tid & 63;
  if (lane == 0) { smx[wid] = mx; smn[wid] = mn; }
  __syncthreads();
  if (tid == 0) {
    kmx[b] = fmaxf(fmaxf(smx[0], smx[1]), fmaxf(smx[2], smx[3]));
    kmn[b] = fminf(fminf(smn[0], smn[1]), fminf(smn[2], smn[3]));
  }
}

__global__ __launch_bounds__(256) void attn_main(
    const float* __restrict__ X, const float* __restrict__ a2,
    const float* __restrict__ kvec, const float* __restrict__ kmx,
    const float* __restrict__ kmn, float* __restrict__ out) {
  __shared__ float xs[64 * DD];
  __shared__ float wt[64 * 32];
  __shared__ float denp[8 * 32];
  const int tid = threadIdx.x;
  const int tx = tid & 15;
  const int ty = (tid >> 4) & 3;
  const int tz = tid >> 6;
  const int b = blockIdx.y;
  const int s0 = blockIdx.x * 32;
  const int sg = tid & 31;
  const int tq = tid >> 5;
  const float ga = a2[b * SS + s0 + sg];
  const float gm = fmaxf(ga * kmx[b], ga * kmn[b]);
  float gden = 0.0f;
  float acc[8][8];
#pragma unroll
  for (int r = 0; r < 8; ++r)
#pragma unroll
    for (int c = 0; c < 8; ++c) acc[r][c] = 0.0f;
  const float* xb = X + (size_t)b * SS * DD;
  const float* kb = kvec + b * SS;
  for (int t0 = 0; t0 < SS; t0 += 64) {
    __syncthreads();
#pragma unroll
    for (int rnd = 0; rnd < 8; ++rnd) {
      const int idx = rnd * 1024 + tid * 4;
      *reinterpret_cast<float4*>(xs + idx) =
          *reinterpret_cast<const float4*>(xb + t0 * DD + idx);
    }
#pragma unroll
    for (int j = 0; j < 8; ++j) {
      const float kt = kb[t0 + tq * 8 + j];
      const float wv = exp2f(fmaf(ga, kt, -gm));
      wt[(tq * 8 + j) * 32 + sg] = wv;
      gden += wv;
    }
    __syncthreads();
#pragma unroll 4
    for (int ti = 0; ti < 16; ++ti) {
      const int tl = tz * 16 + ti;
      const float4 x0 = *reinterpret_cast<const float4*>(xs + tl * DD + tx * 8);
      const float4 x1 = *reinterpret_cast<const float4*>(xs + tl * DD + tx * 8 + 4);
      const float4 w0 = *reinterpret_cast<const float4*>(wt + tl * 32 + ty * 8);
      const float4 w1 = *reinterpret_cast<const float4*>(wt + tl * 32 + ty * 8 + 4);
      const float xr[8] = {x0.x, x0.y, x0.z, x0.w, x1.x, x1.y, x1.z, x1.w};
      const float wr[8] = {w0.x, w0.y, w0.z, w0.w, w1.x, w1.y, w1.z, w1.w};
#pragma unroll
      for (int r = 0; r < 8; ++r)
#pragma unroll
        for (int c = 0; c < 8; ++c) acc[r][c] = fmaf(wr[r], xr[c], acc[r][c]);
    }
  }
  __syncthreads();
  denp[tq * 32 + sg] = gden;
  for (int p = 1; p < 4; ++p) {
    __syncthreads();
    if (tz == p) {
#pragma unroll
      for (int r = 0; r < 8; ++r) {
        const int sl = ty * 8 + r;
        *reinterpret_cast<float4*>(xs + sl * DD + tx * 8) =
            make_float4(acc[r][0], acc[r][1], acc[r][2], acc[r][3]);
        *reinterpret_cast<float4*>(xs + sl * DD + tx * 8 + 4) =
            make_float4(acc[r][4], acc[r][5], acc[r][6], acc[r][7]);
      }
    }
    __syncthreads();
    if (tz == 0) {
#pragma unroll
      for (int r = 0; r < 8; ++r) {
        const int sl = ty * 8 + r;
        const float4 v0 = *reinterpret_cast<const float4*>(xs + sl * DD + tx * 8);
        const float4 v1 = *reinterpret_cast<const float4*>(xs + sl * DD + tx * 8 + 4);
        acc[r][0] += v0.x; acc[r][1] += v0.y; acc[r][2] += v0.z; acc[r][3] += v0.w;
        acc[r][4] += v1.x; acc[r][5] += v1.y; acc[r][6] += v1.z; acc[r][7] += v1.w;
      }
    }
  }
  if (tz == 0) {
#pragma unroll
    for (int r = 0; r < 8; ++r) {
      const int sl = ty * 8 + r;
      float den = 0.0f;
#pragma unroll
      for (int q = 0; q < 8; ++q) den += denp[q * 32 + sl];
      const float inv = 1.0f / den;
      float* orow = out + ((size_t)b * SS + s0 + sl) * DD + tx * 8;
      *reinterpret_cast<float4*>(orow) =
          make_float4(acc[r][0] * inv, acc[r][1] * inv, acc[r][2] * inv, acc[r][3] * inv);
      *reinterpret_cast<float4*>(orow + 4) =
          make_float4(acc[r][4] * inv, acc[r][5] * inv, acc[r][6] * inv, acc[r][7] * inv);
    }
  }
}

extern "C" void kernel_launch(void* const* d_in, const int* in_sizes, int n_in,
                              void* d_out, int out_size, void* d_ws, size_t ws_size,
                              hipStream_t stream) {
  const float* X = (const float*)d_in[0];
  const float* rotp = (const float*)d_in[1];
  const float* entp = (const float*)d_in[2];
  float* out = (float*)d_out;
  uint8_t* ws = (uint8_t*)d_ws;

  if (ws_size >= WS_NEED) {
    prep<<<512, 256, 0, stream>>>(X, rotp, entp, ws, 1);
    attn_mfma<<<512, 512, 0, stream>>>((const uint8_t*)ws, out);
  } else {
    float* a2 = (float*)(ws + WS_A2);
    float* kv = (float*)(ws + WS_KV);
    float* kmxp = (float*)(ws + WS_KMX);
    float* kmnp = (float*)(ws + WS_KMN);
    prep<<<512, 256, 0, stream>>>(X, rotp, entp, ws, 0);
    kminmax<<<NB, 256, 0, stream>>>(kv, kmxp, kmnp);
    attn_main<<<dim3(SS / 32, NB), 256, 0, stream>>>(X, a2, kv, kmxp, kmnp, out);
  }
}